// Round 7
// baseline (228.226 us; speedup 1.0000x reference)
//
#include <hip/hip_runtime.h>
#include <hip/hip_cooperative_groups.h>

namespace cg = cooperative_groups;

// Problem: N=64 graphs, K=64 nodes, C_IN=128, C=128, fp32.
// Single cooperative kernel, 3 phases over grid (12, 64) = 768 blocks
// (= 3 blocks/CU x 256 CUs co-resident; LDS 50.2 KB binds at exactly 3):
//   P1 (j<8): h = x @ W_lin[:, :128].T + b_lin + t*W_lin[:,128]
//   P2 (j<8): binary: A=h@Wb1L.T, Bb=h@Wb1R.T+bb1 (LDS only);
//             U=exp2(k*A), V=exp2(k*Bb); S'=(63-2*sum_{i!=j}rcp(U_j V_i+1))/64
//      (j>=8): unary: T = tanh(h@Wu1.T + bu1)
//   P3 (j<8): out = T@Wu2.T + S'@Wb2.T + bu2 + (63/64)*bb2
// Fallback (if cooperative launch is rejected): R5's 3-kernel pipeline.
#define LS 132  // LDS row stride (dwords): (4l)%32 -> 8 dwords/bank for b128
#define USTR 20 // U/V row stride: (20l)%32 -> 8 dwords/bank
#define ROW_ELEMS 524288  // 4096*128
#define EXPC 2.8853900817779268f  // 2*log2(e)

__device__ __forceinline__ float sigterm(float x) {
    float e = __builtin_amdgcn_exp2f(x * EXPC);
    return __builtin_amdgcn_rcpf(e + 1.0f);
}
__device__ __forceinline__ float tanh_fast(float x) {
    return 1.0f - 2.0f * sigterm(x);
}

__device__ __forceinline__ void stage64(const float* __restrict__ X, int r0,
                                        float* __restrict__ xs, int tid) {
    const float4* src = reinterpret_cast<const float4*>(X + (size_t)r0 * 128);
#pragma unroll
    for (int p = 0; p < 8; ++p) {
        const int q = p * 256 + tid;  // 2048 float4s
        const int r = q >> 5;
        const int k4 = (q & 31) << 2;
        *reinterpret_cast<float4*>(&xs[r * LS + k4]) = src[q];
    }
}

template <int NR, int RS>
__device__ __forceinline__ void stage_w(const float* __restrict__ W, int row0,
                                        float* __restrict__ wt, int tid) {
    if constexpr (RS == 128) {
#pragma unroll
        for (int p = 0; p < NR / 8; ++p) {
            const int q = p * 256 + tid;
            const int row = q >> 5;
            const int k4 = (q & 31) << 2;
            *reinterpret_cast<float4*>(&wt[row * 128 + k4]) =
                *reinterpret_cast<const float4*>(W + (row0 + row) * RS + k4);
        }
    } else {  // odd row stride: scalar-coalesced
#pragma unroll
        for (int p = 0; p < NR / 2; ++p) {
            const int q = p * 256 + tid;
            const int row = q >> 7;
            const int col = q & 127;
            wt[row * 128 + col] = W[(row0 + row) * RS + col];
        }
    }
}

template <int NC>
__device__ __forceinline__ void accum_lds(const float* __restrict__ xs,
                                          const float* __restrict__ wt,
                                          int lane, int wc0,
                                          float (&acc)[NC]) {
#pragma unroll 8
    for (int kq = 0; kq < 32; ++kq) {
        const float4 a =
            *reinterpret_cast<const float4*>(&xs[lane * LS + kq * 4]);
#pragma unroll
        for (int c = 0; c < NC; ++c) {
            const float4 w = *reinterpret_cast<const float4*>(
                &wt[(wc0 + c) * 128 + kq * 4]);
            acc[c] = fmaf(a.x, w.x, acc[c]);
            acc[c] = fmaf(a.y, w.y, acc[c]);
            acc[c] = fmaf(a.z, w.z, acc[c]);
            acc[c] = fmaf(a.w, w.w, acc[c]);
        }
    }
}

__global__ __launch_bounds__(256) void fused_all(
    const float* __restrict__ tp, const float* __restrict__ x,
    const float* __restrict__ W_lin, const float* __restrict__ b_lin,
    const float* __restrict__ Wu1, const float* __restrict__ bu1,
    const float* __restrict__ Wu2, const float* __restrict__ bu2,
    const float* __restrict__ Wb1, const float* __restrict__ bb1,
    const float* __restrict__ Wb2, const float* __restrict__ bb2,
    float* __restrict__ h, float* __restrict__ T, float* __restrict__ S,
    float* __restrict__ out) {
    __shared__ float smem[64 * LS + 32 * 128];
    float* xs = smem;
    float* wt = smem + 64 * LS;
    float* us = smem;              // alias: xs region (dead after P2 GEMM)
    float* vs = smem + 64 * USTR;
    cg::grid_group gg = cg::this_grid();
    const int tid = threadIdx.x;
    const int lane = tid & 63;
    const int wv = __builtin_amdgcn_readfirstlane(tid >> 6);
    const int j = blockIdx.x;   // 0..11
    const int g = blockIdx.y;   // graph
    const int r0 = g * 64;

    // ---------------- Phase 1: h ----------------
    if (j < 8) {
        stage64(x, r0, xs, tid);
        stage_w<16, 129>(W_lin, j * 16, wt, tid);
        __syncthreads();
        float acc[4] = {0.f, 0.f, 0.f, 0.f};
        accum_lds<4>(xs, wt, lane, wv * 4, acc);
        const int c0 = j * 16 + wv * 4;
        const float tv = tp[0];
        float4 o;
        o.x = acc[0] + b_lin[c0 + 0] + tv * W_lin[(c0 + 0) * 129 + 128];
        o.y = acc[1] + b_lin[c0 + 1] + tv * W_lin[(c0 + 1) * 129 + 128];
        o.z = acc[2] + b_lin[c0 + 2] + tv * W_lin[(c0 + 2) * 129 + 128];
        o.w = acc[3] + b_lin[c0 + 3] + tv * W_lin[(c0 + 3) * 129 + 128];
        *reinterpret_cast<float4*>(&h[(size_t)(r0 + lane) * 128 + c0]) = o;
    }
    gg.sync();

    // ---------------- Phase 2: T (unary) + S' (binary) ----------------
    stage64(h, r0, xs, tid);
    {
        const int cb = j < 8 ? j * 16 : 0;
        const int cg0 = j >= 8 ? (j - 8) * 32 : 0;
#pragma unroll
        for (int p = 0; p < 4; ++p) {
            const int q = p * 256 + tid;  // 1024 float4s
            const int row = q >> 5;
            const int k4 = (q & 31) << 2;
            const float* src;
            if (j < 8)
                src = (row < 16) ? (Wb1 + (cb + row) * 256 + k4)
                                 : (Wb1 + (cb + row - 16) * 256 + 128 + k4);
            else
                src = Wu1 + (cg0 + row) * 128 + k4;
            *reinterpret_cast<float4*>(&wt[row * 128 + k4]) =
                *reinterpret_cast<const float4*>(src);
        }
    }
    __syncthreads();

    if (j < 8) {  // ---- binary chunk of 16 channels ----
        const int cb = j * 16;
        const bool isB = wv >= 2;
        const int half = wv & 1;
        const int c0 = cb + half * 8;
        const int wc0 = (isB ? 16 : 0) + half * 8;
        float acc[8] = {0.f, 0.f, 0.f, 0.f, 0.f, 0.f, 0.f, 0.f};
        accum_lds<8>(xs, wt, lane, wc0, acc);
        float e[8];
#pragma unroll
        for (int c = 0; c < 8; ++c) {
            const float v = isB ? (acc[c] + bb1[c0 + c]) : acc[c];
            e[c] = __builtin_amdgcn_exp2f(v * EXPC);
        }
        __syncthreads();  // all waves done reading xs; safe to overwrite
        float* dstl = (isB ? vs : us) + lane * USTR + half * 8;
        *reinterpret_cast<float4*>(dstl) = make_float4(e[0], e[1], e[2], e[3]);
        *reinterpret_cast<float4*>(dstl + 4) =
            make_float4(e[4], e[5], e[6], e[7]);
        __syncthreads();

        const int lc = wv * 4;
        const float4 u =
            *reinterpret_cast<const float4*>(&us[lane * USTR + lc]);
        float s0 = 0.f, s1 = 0.f, s2 = 0.f, s3 = 0.f;
#pragma unroll 8
        for (int i = 0; i < 64; ++i) {
            const float4 v =
                *reinterpret_cast<const float4*>(&vs[i * USTR + lc]);
            s0 += __builtin_amdgcn_rcpf(fmaf(u.x, v.x, 1.0f));
            s1 += __builtin_amdgcn_rcpf(fmaf(u.y, v.y, 1.0f));
            s2 += __builtin_amdgcn_rcpf(fmaf(u.z, v.z, 1.0f));
            s3 += __builtin_amdgcn_rcpf(fmaf(u.w, v.w, 1.0f));
        }
        const float4 vj =
            *reinterpret_cast<const float4*>(&vs[lane * USTR + lc]);
        float4 o;
        o.x = (63.0f - 2.0f * (s0 - __builtin_amdgcn_rcpf(fmaf(u.x, vj.x, 1.0f)))) * 0.015625f;
        o.y = (63.0f - 2.0f * (s1 - __builtin_amdgcn_rcpf(fmaf(u.y, vj.y, 1.0f)))) * 0.015625f;
        o.z = (63.0f - 2.0f * (s2 - __builtin_amdgcn_rcpf(fmaf(u.z, vj.z, 1.0f)))) * 0.015625f;
        o.w = (63.0f - 2.0f * (s3 - __builtin_amdgcn_rcpf(fmaf(u.w, vj.w, 1.0f)))) * 0.015625f;
        *reinterpret_cast<float4*>(&S[(size_t)(r0 + lane) * 128 + cb + lc]) = o;
    } else {  // ---- unary T ----
        const int c0 = (j - 8) * 32 + wv * 8;
        float acc[8] = {0.f, 0.f, 0.f, 0.f, 0.f, 0.f, 0.f, 0.f};
        accum_lds<8>(xs, wt, lane, wv * 8, acc);
        float4 v0, v1;
        v0.x = tanh_fast(acc[0] + bu1[c0 + 0]);
        v0.y = tanh_fast(acc[1] + bu1[c0 + 1]);
        v0.z = tanh_fast(acc[2] + bu1[c0 + 2]);
        v0.w = tanh_fast(acc[3] + bu1[c0 + 3]);
        v1.x = tanh_fast(acc[4] + bu1[c0 + 4]);
        v1.y = tanh_fast(acc[5] + bu1[c0 + 5]);
        v1.z = tanh_fast(acc[6] + bu1[c0 + 6]);
        v1.w = tanh_fast(acc[7] + bu1[c0 + 7]);
        float* dst = T + (size_t)(r0 + lane) * 128 + c0;
        *reinterpret_cast<float4*>(dst) = v0;
        *reinterpret_cast<float4*>(dst + 4) = v1;
    }
    gg.sync();

    // ---------------- Phase 3: out ----------------
    if (j < 8) {
        const int cb = j * 16;
        const int c0 = cb + wv * 4;
        stage64(T, r0, xs, tid);
        stage_w<16, 128>(Wu2, cb, wt, tid);
        stage_w<16, 128>(Wb2, cb, wt + 16 * 128, tid);
        __syncthreads();
        float acc[4] = {0.f, 0.f, 0.f, 0.f};
        accum_lds<4>(xs, wt, lane, wv * 4, acc);
        __syncthreads();
        stage64(S, r0, xs, tid);
        __syncthreads();
        accum_lds<4>(xs, wt, lane, 16 + wv * 4, acc);
        float4 o;
        o.x = acc[0] + bu2[c0 + 0] + 0.984375f * bb2[c0 + 0];
        o.y = acc[1] + bu2[c0 + 1] + 0.984375f * bb2[c0 + 1];
        o.z = acc[2] + bu2[c0 + 2] + 0.984375f * bb2[c0 + 2];
        o.w = acc[3] + bu2[c0 + 3] + 0.984375f * bb2[c0 + 3];
        *reinterpret_cast<float4*>(&out[(size_t)(r0 + lane) * 128 + c0]) = o;
    }
}

// ---------------- Fallback: R5's 3-kernel pipeline ----------------
__global__ __launch_bounds__(256) void k1_h(const float* __restrict__ x,
                                            const float* __restrict__ W_lin,
                                            const float* __restrict__ b_lin,
                                            const float* __restrict__ tp,
                                            float* __restrict__ h) {
    __shared__ float xs[64 * LS];
    const int tid = threadIdx.x;
    const int lane = tid & 63;
    const int wv = __builtin_amdgcn_readfirstlane(tid >> 6);
    const int r0 = blockIdx.y * 64;
    const int c0 = blockIdx.x * 8 + wv * 2;
    stage64(x, r0, xs, tid);
    __syncthreads();
    float acc[2] = {0.f, 0.f};
    const float* w0 = W_lin + (c0 + 0) * 129;
    const float* w1 = W_lin + (c0 + 1) * 129;
#pragma unroll 8
    for (int kq = 0; kq < 32; ++kq) {
        const float4 a =
            *reinterpret_cast<const float4*>(&xs[lane * LS + kq * 4]);
        acc[0] = fmaf(a.x, w0[kq * 4 + 0], acc[0]);
        acc[0] = fmaf(a.y, w0[kq * 4 + 1], acc[0]);
        acc[0] = fmaf(a.z, w0[kq * 4 + 2], acc[0]);
        acc[0] = fmaf(a.w, w0[kq * 4 + 3], acc[0]);
        acc[1] = fmaf(a.x, w1[kq * 4 + 0], acc[1]);
        acc[1] = fmaf(a.y, w1[kq * 4 + 1], acc[1]);
        acc[1] = fmaf(a.z, w1[kq * 4 + 2], acc[1]);
        acc[1] = fmaf(a.w, w1[kq * 4 + 3], acc[1]);
    }
    const float tv = tp[0];
    float2 o;
    o.x = acc[0] + b_lin[c0 + 0] + tv * W_lin[(c0 + 0) * 129 + 128];
    o.y = acc[1] + b_lin[c0 + 1] + tv * W_lin[(c0 + 1) * 129 + 128];
    *reinterpret_cast<float2*>(&h[(size_t)(r0 + lane) * 128 + c0]) = o;
}

__global__ __launch_bounds__(256) void k2_fused(
    const float* __restrict__ h, const float* __restrict__ Wu1,
    const float* __restrict__ bu1, const float* __restrict__ Wb1,
    const float* __restrict__ bb1, float* __restrict__ T,
    float* __restrict__ S) {
    __shared__ float smem[64 * LS + 32 * 128];
    float* xs = smem;
    float* wt = smem + 64 * LS;
    float* us = smem;
    float* vs = smem + 64 * USTR;
    const int tid = threadIdx.x;
    const int lane = tid & 63;
    const int wv = __builtin_amdgcn_readfirstlane(tid >> 6);
    const int r0 = blockIdx.y * 64;
    const int bx = blockIdx.x;
    stage64(h, r0, xs, tid);
    {
        const int cb = bx < 8 ? bx * 16 : 0;
        const int cg0 = bx >= 8 ? (bx - 8) * 32 : 0;
#pragma unroll
        for (int p = 0; p < 4; ++p) {
            const int q = p * 256 + tid;
            const int row = q >> 5;
            const int k4 = (q & 31) << 2;
            const float* src;
            if (bx < 8)
                src = (row < 16) ? (Wb1 + (cb + row) * 256 + k4)
                                 : (Wb1 + (cb + row - 16) * 256 + 128 + k4);
            else
                src = Wu1 + (cg0 + row) * 128 + k4;
            *reinterpret_cast<float4*>(&wt[row * 128 + k4]) =
                *reinterpret_cast<const float4*>(src);
        }
    }
    __syncthreads();
    if (bx < 8) {
        const int cb = bx * 16;
        const bool isB = wv >= 2;
        const int half = wv & 1;
        const int c0 = cb + half * 8;
        const int wc0 = (isB ? 16 : 0) + half * 8;
        float acc[8] = {0.f, 0.f, 0.f, 0.f, 0.f, 0.f, 0.f, 0.f};
        accum_lds<8>(xs, wt, lane, wc0, acc);
        float e[8];
#pragma unroll
        for (int c = 0; c < 8; ++c) {
            const float v = isB ? (acc[c] + bb1[c0 + c]) : acc[c];
            e[c] = __builtin_amdgcn_exp2f(v * EXPC);
        }
        __syncthreads();
        float* dstl = (isB ? vs : us) + lane * USTR + half * 8;
        *reinterpret_cast<float4*>(dstl) = make_float4(e[0], e[1], e[2], e[3]);
        *reinterpret_cast<float4*>(dstl + 4) =
            make_float4(e[4], e[5], e[6], e[7]);
        __syncthreads();
        const int lc = wv * 4;
        const float4 u =
            *reinterpret_cast<const float4*>(&us[lane * USTR + lc]);
        float s0 = 0.f, s1 = 0.f, s2 = 0.f, s3 = 0.f;
#pragma unroll 8
        for (int i = 0; i < 64; ++i) {
            const float4 v =
                *reinterpret_cast<const float4*>(&vs[i * USTR + lc]);
            s0 += __builtin_amdgcn_rcpf(fmaf(u.x, v.x, 1.0f));
            s1 += __builtin_amdgcn_rcpf(fmaf(u.y, v.y, 1.0f));
            s2 += __builtin_amdgcn_rcpf(fmaf(u.z, v.z, 1.0f));
            s3 += __builtin_amdgcn_rcpf(fmaf(u.w, v.w, 1.0f));
        }
        const float4 vj =
            *reinterpret_cast<const float4*>(&vs[lane * USTR + lc]);
        float4 o;
        o.x = (63.0f - 2.0f * (s0 - __builtin_amdgcn_rcpf(fmaf(u.x, vj.x, 1.0f)))) * 0.015625f;
        o.y = (63.0f - 2.0f * (s1 - __builtin_amdgcn_rcpf(fmaf(u.y, vj.y, 1.0f)))) * 0.015625f;
        o.z = (63.0f - 2.0f * (s2 - __builtin_amdgcn_rcpf(fmaf(u.z, vj.z, 1.0f)))) * 0.015625f;
        o.w = (63.0f - 2.0f * (s3 - __builtin_amdgcn_rcpf(fmaf(u.w, vj.w, 1.0f)))) * 0.015625f;
        *reinterpret_cast<float4*>(&S[(size_t)(r0 + lane) * 128 + cb + lc]) = o;
    } else {
        const int c0 = (bx - 8) * 32 + wv * 8;
        float acc[8] = {0.f, 0.f, 0.f, 0.f, 0.f, 0.f, 0.f, 0.f};
        accum_lds<8>(xs, wt, lane, wv * 8, acc);
        float4 v0, v1;
        v0.x = tanh_fast(acc[0] + bu1[c0 + 0]);
        v0.y = tanh_fast(acc[1] + bu1[c0 + 1]);
        v0.z = tanh_fast(acc[2] + bu1[c0 + 2]);
        v0.w = tanh_fast(acc[3] + bu1[c0 + 3]);
        v1.x = tanh_fast(acc[4] + bu1[c0 + 4]);
        v1.y = tanh_fast(acc[5] + bu1[c0 + 5]);
        v1.z = tanh_fast(acc[6] + bu1[c0 + 6]);
        v1.w = tanh_fast(acc[7] + bu1[c0 + 7]);
        float* dst = T + (size_t)(r0 + lane) * 128 + c0;
        *reinterpret_cast<float4*>(dst) = v0;
        *reinterpret_cast<float4*>(dst + 4) = v1;
    }
}

__global__ __launch_bounds__(256) void k4_out(
    const float* __restrict__ T, const float* __restrict__ S,
    const float* __restrict__ Wu2, const float* __restrict__ Wb2,
    const float* __restrict__ bu2, const float* __restrict__ bb2,
    float* __restrict__ out) {
    __shared__ float xs[64 * LS];
    const int tid = threadIdx.x;
    const int lane = tid & 63;
    const int wv = __builtin_amdgcn_readfirstlane(tid >> 6);
    const int r0 = blockIdx.y * 64;
    const int c0 = blockIdx.x * 8 + wv * 2;
    stage64(T, r0, xs, tid);
    __syncthreads();
    float acc[2] = {0.f, 0.f};
    {
        const float* w0 = Wu2 + (c0 + 0) * 128;
        const float* w1 = Wu2 + (c0 + 1) * 128;
#pragma unroll 8
        for (int kq = 0; kq < 32; ++kq) {
            const float4 a =
                *reinterpret_cast<const float4*>(&xs[lane * LS + kq * 4]);
            acc[0] = fmaf(a.x, w0[kq * 4 + 0], acc[0]);
            acc[0] = fmaf(a.y, w0[kq * 4 + 1], acc[0]);
            acc[0] = fmaf(a.z, w0[kq * 4 + 2], acc[0]);
            acc[0] = fmaf(a.w, w0[kq * 4 + 3], acc[0]);
            acc[1] = fmaf(a.x, w1[kq * 4 + 0], acc[1]);
            acc[1] = fmaf(a.y, w1[kq * 4 + 1], acc[1]);
            acc[1] = fmaf(a.z, w1[kq * 4 + 2], acc[1]);
            acc[1] = fmaf(a.w, w1[kq * 4 + 3], acc[1]);
        }
    }
    __syncthreads();
    stage64(S, r0, xs, tid);
    __syncthreads();
    {
        const float* w0 = Wb2 + (c0 + 0) * 128;
        const float* w1 = Wb2 + (c0 + 1) * 128;
#pragma unroll 8
        for (int kq = 0; kq < 32; ++kq) {
            const float4 a =
                *reinterpret_cast<const float4*>(&xs[lane * LS + kq * 4]);
            acc[0] = fmaf(a.x, w0[kq * 4 + 0], acc[0]);
            acc[0] = fmaf(a.y, w0[kq * 4 + 1], acc[0]);
            acc[0] = fmaf(a.z, w0[kq * 4 + 2], acc[0]);
            acc[0] = fmaf(a.w, w0[kq * 4 + 3], acc[0]);
            acc[1] = fmaf(a.x, w1[kq * 4 + 0], acc[1]);
            acc[1] = fmaf(a.y, w1[kq * 4 + 1], acc[1]);
            acc[1] = fmaf(a.z, w1[kq * 4 + 2], acc[1]);
            acc[1] = fmaf(a.w, w1[kq * 4 + 3], acc[1]);
        }
    }
    float2 o;
    o.x = acc[0] + bu2[c0 + 0] + 0.984375f * bb2[c0 + 0];
    o.y = acc[1] + bu2[c0 + 1] + 0.984375f * bb2[c0 + 1];
    *reinterpret_cast<float2*>(&out[(size_t)(r0 + lane) * 128 + c0]) = o;
}

extern "C" void kernel_launch(void* const* d_in, const int* in_sizes, int n_in,
                              void* d_out, int out_size, void* d_ws,
                              size_t ws_size, hipStream_t stream) {
    const float* t = (const float*)d_in[0];
    const float* x = (const float*)d_in[1];
    const float* W_lin = (const float*)d_in[2];
    const float* b_lin = (const float*)d_in[3];
    const float* Wu1 = (const float*)d_in[4];
    const float* bu1 = (const float*)d_in[5];
    const float* Wu2 = (const float*)d_in[6];
    const float* bu2 = (const float*)d_in[7];
    const float* Wb1 = (const float*)d_in[8];
    const float* bb1 = (const float*)d_in[9];
    const float* Wb2 = (const float*)d_in[10];
    const float* bb2 = (const float*)d_in[11];
    float* out = (float*)d_out;

    float* ws = (float*)d_ws;
    float* h = ws;
    float* T = ws + 1 * ROW_ELEMS;
    float* S = ws + 2 * ROW_ELEMS;

    void* args[] = {(void*)&t,   (void*)&x,   (void*)&W_lin, (void*)&b_lin,
                    (void*)&Wu1, (void*)&bu1, (void*)&Wu2,   (void*)&bu2,
                    (void*)&Wb1, (void*)&bb1, (void*)&Wb2,   (void*)&bb2,
                    (void*)&h,   (void*)&T,   (void*)&S,     (void*)&out};
    hipError_t err = hipLaunchCooperativeKernel(
        (const void*)fused_all, dim3(12, 64), dim3(256), args, 0, stream);
    if (err != hipSuccess) {
        // Fallback: R5 3-kernel pipeline (deterministic per-machine).
        k1_h<<<dim3(16, 64), 256, 0, stream>>>(x, W_lin, b_lin, t, h);
        k2_fused<<<dim3(12, 64), 256, 0, stream>>>(h, Wu1, bu1, Wb1, bb1, T, S);
        k4_out<<<dim3(16, 64), 256, 0, stream>>>(T, S, Wu2, Wb2, bu2, bb2, out);
    }
    (void)in_sizes; (void)n_in; (void)out_size; (void)ws_size;
}

// Round 8
// 32.797 us; speedup vs baseline: 6.9588x; 6.9588x over previous
//
#include <hip/hip_runtime.h>

// Problem: N=64 graphs, K=64 nodes, C_IN=128, C=128, fp32.
// R5 pipeline + XCD-local grid mapping: blockIdx.x = graph everywhere, so
// linear_id % 8 == graph % 8 -> all blocks touching a graph's h/T/S' tiles
// land on ONE XCD; inter-kernel tensors stay in that XCD's L2.
//   K1: h = x @ W_lin[:, :128].T + b_lin + t*W_lin[:,128]
//   K2f: binary blocks: A=h@Wb1L.T, Bb=h@Wb1R.T+bb1 (LDS only);
//          U=exp2(k*A), V=exp2(k*Bb); S'=(63-2*sum_{i!=j}rcp(U_j V_i+1))/64
//        unary blocks: T = tanh(h@Wu1.T + bu1)
//   K4: out = T@Wu2.T + S'@Wb2.T + bu2 + (63/64)*bb2
#define LS 132  // LDS row stride (dwords): (4l)%32 -> 8 dwords/bank for b128
#define USTR 20 // U/V row stride: (20l)%32 -> 8 dwords/bank
#define ROW_ELEMS 524288  // 4096*128
#define EXPC 2.8853900817779268f  // 2*log2(e)

__device__ __forceinline__ float sigterm(float x) {
    float e = __builtin_amdgcn_exp2f(x * EXPC);
    return __builtin_amdgcn_rcpf(e + 1.0f);
}
__device__ __forceinline__ float tanh_fast(float x) {
    return 1.0f - 2.0f * sigterm(x);
}

__device__ __forceinline__ void stage64(const float* __restrict__ X, int r0,
                                        float* __restrict__ xs, int tid) {
    const float4* src = reinterpret_cast<const float4*>(X + (size_t)r0 * 128);
#pragma unroll
    for (int p = 0; p < 8; ++p) {
        const int q = p * 256 + tid;  // 2048 float4s
        const int r = q >> 5;
        const int k4 = (q & 31) << 2;
        *reinterpret_cast<float4*>(&xs[r * LS + k4]) = src[q];
    }
}

// LDS-staged weight broadcast inner product (K2f).
template <int NC>
__device__ __forceinline__ void accum_lds(const float* __restrict__ xs,
                                          const float* __restrict__ wt,
                                          int lane, int wc0,
                                          float (&acc)[NC]) {
#pragma unroll 8
    for (int kq = 0; kq < 32; ++kq) {
        const float4 a =
            *reinterpret_cast<const float4*>(&xs[lane * LS + kq * 4]);
#pragma unroll
        for (int c = 0; c < NC; ++c) {
            const float4 w = *reinterpret_cast<const float4*>(
                &wt[(wc0 + c) * 128 + kq * 4]);
            acc[c] = fmaf(a.x, w.x, acc[c]);
            acc[c] = fmaf(a.y, w.y, acc[c]);
            acc[c] = fmaf(a.z, w.z, acc[c]);
            acc[c] = fmaf(a.w, w.w, acc[c]);
        }
    }
}

// K1: h = x@W_lin[:,:128].T + b_lin + t*W_lin[:,128]. 2 cols/wave.
// grid (64, 16): bx = graph -> XCD-local h writes. 1024 blocks, 4/CU.
__global__ __launch_bounds__(256) void k1_h(const float* __restrict__ x,
                                            const float* __restrict__ W_lin,
                                            const float* __restrict__ b_lin,
                                            const float* __restrict__ tp,
                                            float* __restrict__ h) {
    __shared__ float xs[64 * LS];
    const int tid = threadIdx.x;
    const int lane = tid & 63;
    const int wv = __builtin_amdgcn_readfirstlane(tid >> 6);
    const int r0 = blockIdx.x * 64;                 // graph
    const int c0 = blockIdx.y * 8 + wv * 2;         // col pair
    stage64(x, r0, xs, tid);
    __syncthreads();
    float acc[2] = {0.f, 0.f};
    const float* w0 = W_lin + (c0 + 0) * 129;
    const float* w1 = W_lin + (c0 + 1) * 129;
#pragma unroll 8
    for (int kq = 0; kq < 32; ++kq) {
        const float4 a =
            *reinterpret_cast<const float4*>(&xs[lane * LS + kq * 4]);
        acc[0] = fmaf(a.x, w0[kq * 4 + 0], acc[0]);
        acc[0] = fmaf(a.y, w0[kq * 4 + 1], acc[0]);
        acc[0] = fmaf(a.z, w0[kq * 4 + 2], acc[0]);
        acc[0] = fmaf(a.w, w0[kq * 4 + 3], acc[0]);
        acc[1] = fmaf(a.x, w1[kq * 4 + 0], acc[1]);
        acc[1] = fmaf(a.y, w1[kq * 4 + 1], acc[1]);
        acc[1] = fmaf(a.z, w1[kq * 4 + 2], acc[1]);
        acc[1] = fmaf(a.w, w1[kq * 4 + 3], acc[1]);
    }
    const float tv = tp[0];
    float2 o;
    o.x = acc[0] + b_lin[c0 + 0] + tv * W_lin[(c0 + 0) * 129 + 128];
    o.y = acc[1] + b_lin[c0 + 1] + tv * W_lin[(c0 + 1) * 129 + 128];
    *reinterpret_cast<float2*>(&h[(size_t)(r0 + lane) * 128 + c0]) = o;
}

// K2f: grid (64, 12): bx = graph (XCD-local h reads / T,S' writes).
//      by < 8  -> binary chunk of 16 channels (dispatched first)
//      by >= 8 -> unary T cols (32/block, 8/wave)
__global__ __launch_bounds__(256) void k2_fused(
    const float* __restrict__ h, const float* __restrict__ Wu1,
    const float* __restrict__ bu1, const float* __restrict__ Wb1,
    const float* __restrict__ bb1, float* __restrict__ T,
    float* __restrict__ S) {
    __shared__ float smem[64 * LS + 32 * 128];
    float* xs = smem;
    float* wt = smem + 64 * LS;
    float* us = smem;              // alias: xs region (dead after GEMM)
    float* vs = smem + 64 * USTR;
    const int tid = threadIdx.x;
    const int lane = tid & 63;
    const int wv = __builtin_amdgcn_readfirstlane(tid >> 6);
    const int r0 = blockIdx.x * 64;  // graph * 64
    const int j = blockIdx.y;        // role 0..11
    stage64(h, r0, xs, tid);
    {   // Stage 32 weight rows (binary: 16 A-rows + 16 B-rows; unary: 32 Wu1)
        const int cb = j < 8 ? j * 16 : 0;
        const int cg0 = j >= 8 ? (j - 8) * 32 : 0;
#pragma unroll
        for (int p = 0; p < 4; ++p) {
            const int q = p * 256 + tid;  // 1024 float4s
            const int row = q >> 5;
            const int k4 = (q & 31) << 2;
            const float* src;
            if (j < 8)
                src = (row < 16) ? (Wb1 + (cb + row) * 256 + k4)
                                 : (Wb1 + (cb + row - 16) * 256 + 128 + k4);
            else
                src = Wu1 + (cg0 + row) * 128 + k4;
            *reinterpret_cast<float4*>(&wt[row * 128 + k4]) =
                *reinterpret_cast<const float4*>(src);
        }
    }
    __syncthreads();

    if (j < 8) {  // ---- binary chunk ----
        const int cb = j * 16;
        const bool isB = wv >= 2;
        const int half = wv & 1;
        const int c0 = cb + half * 8;
        const int wc0 = (isB ? 16 : 0) + half * 8;
        float acc[8] = {0.f, 0.f, 0.f, 0.f, 0.f, 0.f, 0.f, 0.f};
        accum_lds<8>(xs, wt, lane, wc0, acc);
        float e[8];
#pragma unroll
        for (int c = 0; c < 8; ++c) {
            const float v = isB ? (acc[c] + bb1[c0 + c]) : acc[c];
            e[c] = __builtin_amdgcn_exp2f(v * EXPC);
        }
        __syncthreads();  // all waves done reading xs; safe to overwrite
        float* dstl = (isB ? vs : us) + lane * USTR + half * 8;
        *reinterpret_cast<float4*>(dstl) = make_float4(e[0], e[1], e[2], e[3]);
        *reinterpret_cast<float4*>(dstl + 4) =
            make_float4(e[4], e[5], e[6], e[7]);
        __syncthreads();

        const int lc = wv * 4;
        const float4 u =
            *reinterpret_cast<const float4*>(&us[lane * USTR + lc]);
        float s0 = 0.f, s1 = 0.f, s2 = 0.f, s3 = 0.f;
#pragma unroll 8
        for (int i = 0; i < 64; ++i) {
            const float4 v =
                *reinterpret_cast<const float4*>(&vs[i * USTR + lc]);
            s0 += __builtin_amdgcn_rcpf(fmaf(u.x, v.x, 1.0f));
            s1 += __builtin_amdgcn_rcpf(fmaf(u.y, v.y, 1.0f));
            s2 += __builtin_amdgcn_rcpf(fmaf(u.z, v.z, 1.0f));
            s3 += __builtin_amdgcn_rcpf(fmaf(u.w, v.w, 1.0f));
        }
        const float4 vj =
            *reinterpret_cast<const float4*>(&vs[lane * USTR + lc]);
        float4 o;
        o.x = (63.0f - 2.0f * (s0 - __builtin_amdgcn_rcpf(fmaf(u.x, vj.x, 1.0f)))) * 0.015625f;
        o.y = (63.0f - 2.0f * (s1 - __builtin_amdgcn_rcpf(fmaf(u.y, vj.y, 1.0f)))) * 0.015625f;
        o.z = (63.0f - 2.0f * (s2 - __builtin_amdgcn_rcpf(fmaf(u.z, vj.z, 1.0f)))) * 0.015625f;
        o.w = (63.0f - 2.0f * (s3 - __builtin_amdgcn_rcpf(fmaf(u.w, vj.w, 1.0f)))) * 0.015625f;
        *reinterpret_cast<float4*>(&S[(size_t)(r0 + lane) * 128 + cb + lc]) = o;
    } else {  // ---- unary T ----
        const int c0 = (j - 8) * 32 + wv * 8;
        float acc[8] = {0.f, 0.f, 0.f, 0.f, 0.f, 0.f, 0.f, 0.f};
        accum_lds<8>(xs, wt, lane, wv * 8, acc);
        float4 v0, v1;
        v0.x = tanh_fast(acc[0] + bu1[c0 + 0]);
        v0.y = tanh_fast(acc[1] + bu1[c0 + 1]);
        v0.z = tanh_fast(acc[2] + bu1[c0 + 2]);
        v0.w = tanh_fast(acc[3] + bu1[c0 + 3]);
        v1.x = tanh_fast(acc[4] + bu1[c0 + 4]);
        v1.y = tanh_fast(acc[5] + bu1[c0 + 5]);
        v1.z = tanh_fast(acc[6] + bu1[c0 + 6]);
        v1.w = tanh_fast(acc[7] + bu1[c0 + 7]);
        float* dst = T + (size_t)(r0 + lane) * 128 + c0;
        *reinterpret_cast<float4*>(dst) = v0;
        *reinterpret_cast<float4*>(dst + 4) = v1;
    }
}

// K4: out = T@Wu2.T + S'@Wb2.T + bu2 + (63/64)*bb2. grid (64, 16):
// bx = graph (XCD-local T/S' reads). Two 128-k passes over one xs tile.
__global__ __launch_bounds__(256) void k4_out(
    const float* __restrict__ T, const float* __restrict__ S,
    const float* __restrict__ Wu2, const float* __restrict__ Wb2,
    const float* __restrict__ bu2, const float* __restrict__ bb2,
    float* __restrict__ out) {
    __shared__ float xs[64 * LS];
    const int tid = threadIdx.x;
    const int lane = tid & 63;
    const int wv = __builtin_amdgcn_readfirstlane(tid >> 6);
    const int r0 = blockIdx.x * 64;
    const int c0 = blockIdx.y * 8 + wv * 2;
    stage64(T, r0, xs, tid);
    __syncthreads();
    float acc[2] = {0.f, 0.f};
    {
        const float* w0 = Wu2 + (c0 + 0) * 128;
        const float* w1 = Wu2 + (c0 + 1) * 128;
#pragma unroll 8
        for (int kq = 0; kq < 32; ++kq) {
            const float4 a =
                *reinterpret_cast<const float4*>(&xs[lane * LS + kq * 4]);
            acc[0] = fmaf(a.x, w0[kq * 4 + 0], acc[0]);
            acc[0] = fmaf(a.y, w0[kq * 4 + 1], acc[0]);
            acc[0] = fmaf(a.z, w0[kq * 4 + 2], acc[0]);
            acc[0] = fmaf(a.w, w0[kq * 4 + 3], acc[0]);
            acc[1] = fmaf(a.x, w1[kq * 4 + 0], acc[1]);
            acc[1] = fmaf(a.y, w1[kq * 4 + 1], acc[1]);
            acc[1] = fmaf(a.z, w1[kq * 4 + 2], acc[1]);
            acc[1] = fmaf(a.w, w1[kq * 4 + 3], acc[1]);
        }
    }
    __syncthreads();
    stage64(S, r0, xs, tid);
    __syncthreads();
    {
        const float* w0 = Wb2 + (c0 + 0) * 128;
        const float* w1 = Wb2 + (c0 + 1) * 128;
#pragma unroll 8
        for (int kq = 0; kq < 32; ++kq) {
            const float4 a =
                *reinterpret_cast<const float4*>(&xs[lane * LS + kq * 4]);
            acc[0] = fmaf(a.x, w0[kq * 4 + 0], acc[0]);
            acc[0] = fmaf(a.y, w0[kq * 4 + 1], acc[0]);
            acc[0] = fmaf(a.z, w0[kq * 4 + 2], acc[0]);
            acc[0] = fmaf(a.w, w0[kq * 4 + 3], acc[0]);
            acc[1] = fmaf(a.x, w1[kq * 4 + 0], acc[1]);
            acc[1] = fmaf(a.y, w1[kq * 4 + 1], acc[1]);
            acc[1] = fmaf(a.z, w1[kq * 4 + 2], acc[1]);
            acc[1] = fmaf(a.w, w1[kq * 4 + 3], acc[1]);
        }
    }
    float2 o;
    o.x = acc[0] + bu2[c0 + 0] + 0.984375f * bb2[c0 + 0];
    o.y = acc[1] + bu2[c0 + 1] + 0.984375f * bb2[c0 + 1];
    *reinterpret_cast<float2*>(&out[(size_t)(r0 + lane) * 128 + c0]) = o;
}

extern "C" void kernel_launch(void* const* d_in, const int* in_sizes, int n_in,
                              void* d_out, int out_size, void* d_ws,
                              size_t ws_size, hipStream_t stream) {
    const float* t = (const float*)d_in[0];
    const float* x = (const float*)d_in[1];
    const float* W_lin = (const float*)d_in[2];
    const float* b_lin = (const float*)d_in[3];
    const float* Wu1 = (const float*)d_in[4];
    const float* bu1 = (const float*)d_in[5];
    const float* Wu2 = (const float*)d_in[6];
    const float* bu2 = (const float*)d_in[7];
    const float* Wb1 = (const float*)d_in[8];
    const float* bb1 = (const float*)d_in[9];
    const float* Wb2 = (const float*)d_in[10];
    const float* bb2 = (const float*)d_in[11];
    float* out = (float*)d_out;

    float* ws = (float*)d_ws;
    float* h = ws;
    float* T = ws + 1 * ROW_ELEMS;
    float* S = ws + 2 * ROW_ELEMS;

    // All grids: blockIdx.x = graph -> linear_id % 8 == graph % 8 (XCD-local).
    k1_h<<<dim3(64, 16), 256, 0, stream>>>(x, W_lin, b_lin, t, h);
    k2_fused<<<dim3(64, 12), 256, 0, stream>>>(h, Wu1, bu1, Wb1, bb1, T, S);
    k4_out<<<dim3(64, 16), 256, 0, stream>>>(T, S, Wu2, Wb2, bu2, bb2, out);
    (void)in_sizes; (void)n_in; (void)out_size; (void)ws_size;
}